// Round 1
// baseline (689.847 us; speedup 1.0000x reference)
//
#include <hip/hip_runtime.h>

// FastLoRAEmbedding: out[t,d] = weight[x[t],d] + 16.0 * sum_r a_rows[t,r]*lora_B[d,r]
// Inputs (setup_inputs order): x int32 [4,4096], weight f32 [50257,2048],
// lora_A f32 [64,50257], lora_B f32 [2048,64]. Output f32 [4,4096,2048].

constexpr int VOCAB = 50257;
constexpr int DIM = 2048;
constexpr int R = 64;
constexpr float SCALING = 16.0f;   // 128 / sqrt(64)
constexpr int T_TILE = 64;         // tokens per block in fused kernel
constexpr int BLOCK = 256;

// Stage 1: a_rows[t*R + r] = lora_A[r*VOCAB + x[t]]
// Makes per-token LoRA-A rows contiguous so stage 2 can use wave-uniform
// (scalar) loads. Writes are fully coalesced; reads are scattered but the
// 12.9 MB lora_A table is L2/L3 resident.
__global__ void gather_a_kernel(const int* __restrict__ x,
                                const float* __restrict__ lora_A,
                                float* __restrict__ a_rows,
                                int n_tokens) {
  int gid = blockIdx.x * blockDim.x + threadIdx.x;
  if (gid >= n_tokens * R) return;
  int t = gid >> 6;          // R == 64
  int r = gid & (R - 1);
  int tok = x[t];
  a_rows[gid] = lora_A[(size_t)r * VOCAB + (size_t)tok];
}

// Stage 2: fused gather + rank-64 dot + scale + add + store.
// threadIdx.x <-> one d column (b-row lives in 64 VGPRs, loaded once).
// Loop over T_TILE tokens; token id and a_row address are wave-uniform ->
// compiler should emit s_load for them (SMEM pipe, free VALU-wise).
template <bool USE_WS>
__global__ void fused_kernel(const int* __restrict__ x,
                             const float* __restrict__ weight,
                             const float* __restrict__ lora_A,
                             const float* __restrict__ a_rows,
                             const float* __restrict__ lora_B,
                             float* __restrict__ out) {
  const int d = blockIdx.y * BLOCK + threadIdx.x;
  const int t0 = blockIdx.x * T_TILE;

  // Load this thread's lora_B row (64 contiguous floats) into registers.
  float b[R];
  const float* bp = lora_B + (size_t)d * R;
#pragma unroll
  for (int i = 0; i < R; i += 4) {
    float4 v = *reinterpret_cast<const float4*>(bp + i);
    b[i] = v.x; b[i + 1] = v.y; b[i + 2] = v.z; b[i + 3] = v.w;
  }

#pragma unroll 1
  for (int tt = 0; tt < T_TILE; ++tt) {
    const int t = t0 + tt;
    const int tok = x[t];  // uniform -> s_load

    float a0 = 0.f, a1 = 0.f, a2 = 0.f, a3 = 0.f;
    if (USE_WS) {
      const float* ap = a_rows + (size_t)t * R;  // uniform base
#pragma unroll
      for (int r = 0; r < R; r += 4) {
        a0 += ap[r + 0] * b[r + 0];
        a1 += ap[r + 1] * b[r + 1];
        a2 += ap[r + 2] * b[r + 2];
        a3 += ap[r + 3] * b[r + 3];
      }
    } else {
      // Fallback if d_ws is too small: gather lora_A column directly.
      // Addresses are still wave-uniform (tok uniform).
#pragma unroll
      for (int r = 0; r < R; r += 4) {
        a0 += lora_A[(size_t)(r + 0) * VOCAB + tok] * b[r + 0];
        a1 += lora_A[(size_t)(r + 1) * VOCAB + tok] * b[r + 1];
        a2 += lora_A[(size_t)(r + 2) * VOCAB + tok] * b[r + 2];
        a3 += lora_A[(size_t)(r + 3) * VOCAB + tok] * b[r + 3];
      }
    }
    const float acc = (a0 + a1) + (a2 + a3);

    // Coalesced: lane i reads/writes column d = blockIdx.y*256 + i.
    const float w = weight[(size_t)tok * DIM + d];
    out[(size_t)t * DIM + d] = w + SCALING * acc;
  }
}

extern "C" void kernel_launch(void* const* d_in, const int* in_sizes, int n_in,
                              void* d_out, int out_size, void* d_ws, size_t ws_size,
                              hipStream_t stream) {
  const int* x = (const int*)d_in[0];
  const float* weight = (const float*)d_in[1];
  const float* lora_A = (const float*)d_in[2];
  const float* lora_B = (const float*)d_in[3];
  float* out = (float*)d_out;

  const int n_tokens = in_sizes[0];               // 16384
  const size_t ws_need = (size_t)n_tokens * R * sizeof(float);  // 4 MB
  const bool use_ws = (d_ws != nullptr) && (ws_size >= ws_need);

  dim3 grid(n_tokens / T_TILE, DIM / BLOCK);      // (256, 8)

  if (use_ws) {
    float* a_rows = (float*)d_ws;
    const int total = n_tokens * R;
    gather_a_kernel<<<(total + BLOCK - 1) / BLOCK, BLOCK, 0, stream>>>(
        x, lora_A, a_rows, n_tokens);
    fused_kernel<true><<<grid, BLOCK, 0, stream>>>(
        x, weight, lora_A, a_rows, lora_B, out);
  } else {
    fused_kernel<false><<<grid, BLOCK, 0, stream>>>(
        x, weight, lora_A, nullptr, lora_B, out);
  }
}

// Round 2
// 647.850 us; speedup vs baseline: 1.0648x; 1.0648x over previous
//
#include <hip/hip_runtime.h>

// FastLoRAEmbedding: out[t,d] = weight[x[t],d] + 16.0 * sum_r a_rows[t,r]*lora_B[d,r]
// x int32 [16384], weight f32 [50257,2048], lora_A f32 [64,50257],
// lora_B f32 [2048,64]. Output f32 [16384, 2048].

constexpr int VOCAB = 50257;
constexpr int DIM = 2048;
constexpr int R = 64;
constexpr float SCALING = 16.0f;   // 128 / sqrt(64)

constexpr int T_TILE = 64;   // tokens per block
constexpr int D_TILE = 64;   // d columns per block (= one wave width)
constexpr int WAVE_T = 16;   // tokens per wave (4 waves, disjoint token sets)
constexpr int BLOCK = 256;

// Stage 1: a_rows[t*R + r] = lora_A[r*VOCAB + x[t]]  (coalesced writes;
// scattered reads hit the L2/L3-resident 12.9 MB lora_A table).
__global__ void gather_a_kernel(const int* __restrict__ x,
                                const float* __restrict__ lora_A,
                                float* __restrict__ a_rows,
                                int n_tokens) {
  int gid = blockIdx.x * blockDim.x + threadIdx.x;
  if (gid >= n_tokens * R) return;
  int t = gid >> 6;          // R == 64
  int r = gid & (R - 1);
  int tok = x[t];
  a_rows[gid] = lora_A[(size_t)r * VOCAB + (size_t)tok];
}

// Stage 2: block covers 64 d-columns x 64 tokens. Wave w owns tokens
// [w*16, w*16+16) -> no redundant a-reads across waves; lane <-> d keeps
// weight loads and out stores coalesced (256 B = 4 full lines per access).
// a-tile (16 KB) staged in LDS with one cooperative float4 load; inner
// loop reads it via broadcast ds_read_b128 (conflict-free).
__global__ __launch_bounds__(BLOCK) void fused_kernel(
    const int* __restrict__ x,
    const float* __restrict__ weight,
    const float* __restrict__ a_rows,
    const float* __restrict__ lora_B,
    float* __restrict__ out) {
  __shared__ float sA[T_TILE * R];       // 16 KB
  __shared__ int sTok[T_TILE];

  const int tid = threadIdx.x;
  const int wave = tid >> 6;
  const int lane = tid & 63;
  const int d = blockIdx.y * D_TILE + lane;
  const int t0 = blockIdx.x * T_TILE;

  // Cooperative staging: token ids + a-tile (4096 floats = 1024 float4).
  if (tid < T_TILE) sTok[tid] = x[t0 + tid];
  {
    const float4* __restrict__ src =
        reinterpret_cast<const float4*>(a_rows + (size_t)t0 * R);
    float4* dst = reinterpret_cast<float4*>(sA);
#pragma unroll
    for (int i = 0; i < 4; ++i) dst[tid + BLOCK * i] = src[tid + BLOCK * i];
  }

  // This thread's lora_B row (64 contiguous floats) into registers.
  float b[R];
  {
    const float4* __restrict__ bp =
        reinterpret_cast<const float4*>(lora_B + (size_t)d * R);
#pragma unroll
    for (int i = 0; i < R / 4; ++i) {
      float4 v = bp[i];
      b[4 * i] = v.x; b[4 * i + 1] = v.y; b[4 * i + 2] = v.z; b[4 * i + 3] = v.w;
    }
  }
  __syncthreads();

  const int twbase = wave * WAVE_T;  // this wave's first token within the tile

#pragma unroll 4
  for (int tt = 0; tt < WAVE_T; ++tt) {
    const int tloc = twbase + tt;
    const int tok = sTok[tloc];                       // LDS broadcast
    const float w = weight[(size_t)tok * DIM + d];   // coalesced, independent
                                                     // across unrolled iters
    const float* __restrict__ a = sA + tloc * R;
    float a0 = 0.f, a1 = 0.f, a2 = 0.f, a3 = 0.f;
#pragma unroll
    for (int r = 0; r < R; r += 4) {
      // float4-wide LDS broadcast reads (ds_read_b128, same addr all lanes)
      float4 av = *reinterpret_cast<const float4*>(a + r);
      a0 += av.x * b[r + 0];
      a1 += av.y * b[r + 1];
      a2 += av.z * b[r + 2];
      a3 += av.w * b[r + 3];
    }
    const float acc = (a0 + a1) + (a2 + a3);
    out[(size_t)(t0 + tloc) * DIM + d] = w + SCALING * acc;
  }
}

extern "C" void kernel_launch(void* const* d_in, const int* in_sizes, int n_in,
                              void* d_out, int out_size, void* d_ws, size_t ws_size,
                              hipStream_t stream) {
  const int* x = (const int*)d_in[0];
  const float* weight = (const float*)d_in[1];
  const float* lora_A = (const float*)d_in[2];
  const float* lora_B = (const float*)d_in[3];
  float* out = (float*)d_out;

  const int n_tokens = in_sizes[0];               // 16384
  float* a_rows = (float*)d_ws;                   // 4 MB of ws

  const int total = n_tokens * R;
  gather_a_kernel<<<(total + BLOCK - 1) / BLOCK, BLOCK, 0, stream>>>(
      x, lora_A, a_rows, n_tokens);

  dim3 grid(n_tokens / T_TILE, DIM / D_TILE);     // (256, 32) = 8192 blocks
  fused_kernel<<<grid, BLOCK, 0, stream>>>(x, weight, a_rows, lora_B, out);
}